// Round 1
// baseline (366.639 us; speedup 1.0000x reference)
//
#include <hip/hip_runtime.h>
#include <hip/hip_bf16.h>
#include <cstdint>
#include <cstddef>

#define BSZ 8
#define NN 2048
#define HH 512

typedef __attribute__((ext_vector_type(4))) float f32x4;
typedef __attribute__((ext_vector_type(8))) short short8;
typedef __attribute__((ext_vector_type(4))) unsigned short us4;

static __device__ __forceinline__ unsigned short f2bf(float f) {
    uint32_t u = __builtin_bit_cast(uint32_t, f);
    u += 0x7fffu + ((u >> 16) & 1u);
    return (unsigned short)(u >> 16);
}

static __device__ __forceinline__ void async16(const unsigned short* g, unsigned short* l) {
    __builtin_amdgcn_global_load_lds(
        (const __attribute__((address_space(1))) void*)g,
        (__attribute__((address_space(3))) void*)l, 16, 0, 0);
}

// ---------------- K0a: fp32 -> bf16 conversion (float4 per thread) ----------------
__global__ __launch_bounds__(256) void cvt_bf16_k(const float* __restrict__ s,
                                                  unsigned short* __restrict__ d, int n4) {
    int i = blockIdx.x * 256 + threadIdx.x;
    if (i >= n4) return;
    f32x4 v = ((const f32x4*)s)[i];
    us4 o;
    o[0] = f2bf(v[0]); o[1] = f2bf(v[1]); o[2] = f2bf(v[2]); o[3] = f2bf(v[3]);
    ((us4*)d)[i] = o;
}

// ---------------- K0b: effective q/k weights: wq[h] = sum_o fc_w[o,h]*q_w[o] ------
__global__ __launch_bounds__(256) void eff_w_kernel(
    const float* __restrict__ fc_w, const float* __restrict__ fc_b,
    const float* __restrict__ q_w, const float* __restrict__ q_b,
    const float* __restrict__ k_w, const float* __restrict__ k_b,
    float* __restrict__ wq, float* __restrict__ wk, float* __restrict__ bqk) {
    int h = blockIdx.x * 256 + threadIdx.x;
    float sq = 0.f, sk = 0.f;
    for (int o = 0; o < HH; ++o) {
        float w = fc_w[o * HH + h];
        sq += w * q_w[o];
        sk += w * k_w[o];
    }
    wq[h] = sq; wk[h] = sk;
    if (blockIdx.x == 0) {
        int t = threadIdx.x;
        float bq = fc_b[t] * q_w[t] + fc_b[t + 256] * q_w[t + 256];
        float bk = fc_b[t] * k_w[t] + fc_b[t + 256] * k_w[t + 256];
        for (int off = 32; off; off >>= 1) {
            bq += __shfl_down(bq, off, 64);
            bk += __shfl_down(bk, off, 64);
        }
        __shared__ float rb[8];
        int wv = t >> 6, ln = t & 63;
        if (ln == 0) { rb[wv] = bq; rb[4 + wv] = bk; }
        __syncthreads();
        if (t == 0) bqk[0] = rb[0] + rb[1] + rb[2] + rb[3] + q_b[0];
        if (t == 1) bqk[1] = rb[4] + rb[5] + rb[6] + rb[7] + k_b[0];
    }
}

// ---------------- K1: per-row q,k scalars from fp32 feats -------------------------
__global__ __launch_bounds__(256) void qk_kernel(
    const float* __restrict__ feats, const float* __restrict__ wq,
    const float* __restrict__ wk, const float* __restrict__ bqk,
    float* __restrict__ q, float* __restrict__ k) {
    __shared__ float swq[HH], swk[HH];
    const int t = threadIdx.x;
    swq[t] = wq[t]; swq[t + 256] = wq[t + 256];
    swk[t] = wk[t]; swk[t + 256] = wk[t + 256];
    __syncthreads();
    const int wave = t >> 6, lane = t & 63;
    const int row = blockIdx.x * 4 + wave;
    const float* fr = feats + (size_t)row * HH + lane * 8;
    f32x4 v0 = *(const f32x4*)fr;
    f32x4 v1 = *(const f32x4*)(fr + 4);
    const int base = lane * 8;
    float sq = 0.f, sk = 0.f;
#pragma unroll
    for (int c = 0; c < 4; ++c) { sq += v0[c] * swq[base + c];     sk += v0[c] * swk[base + c]; }
#pragma unroll
    for (int c = 0; c < 4; ++c) { sq += v1[c] * swq[base + 4 + c]; sk += v1[c] * swk[base + 4 + c]; }
    for (int off = 32; off; off >>= 1) {
        sq += __shfl_down(sq, off, 64);
        sk += __shfl_down(sk, off, 64);
    }
    if (lane == 0) { q[row] = sq + bqk[0]; k[row] = sk + bqk[1]; }
}

// ---------------- K2: GEMM1  fpT[b][o][i] = sum_h feats[b,i,h]*fc_w[o,h] + fc_b[o] --
// A = feats_bf [16384][512] (k-major), Bt = fcw_bf [512][512] (k-major).
// 128x128 tile, BK=32, 256 threads (4 waves in 2x2), global_load_lds width 16.
__global__ __launch_bounds__(256) void gemm_fp_kernel(
    const unsigned short* __restrict__ A, const unsigned short* __restrict__ Bt,
    const float* __restrict__ fc_b, unsigned short* __restrict__ fpT) {
    __shared__ alignas(16) unsigned short As[128 * 32];
    __shared__ alignas(16) unsigned short Bs[128 * 32];
    const int tid = threadIdx.x;
    const int wave = tid >> 6, lane = tid & 63;
    const int wi = wave >> 1, wj = wave & 1;
    const int bid = blockIdx.x;
    const int n0 = (bid & 3) * 128;
    const int i0 = (bid >> 2) * 128;
    const int K = HH;
    f32x4 acc[4][4];
#pragma unroll
    for (int a = 0; a < 4; ++a)
#pragma unroll
        for (int b = 0; b < 4; ++b) acc[a][b] = (f32x4)(0.f);

    const int lrow = lane >> 2;        // 0..15
    const int lseg = (lane & 3) * 8;   // 0,8,16,24 elements
    const int fro = (lane & 15) * 32 + (lane >> 4) * 8;

    for (int k0 = 0; k0 < K; k0 += 32) {
        __syncthreads();
        {
            const int c0 = wave * 2;
            const unsigned short* ga = A + (size_t)(i0 + c0 * 16 + lrow) * K + k0 + lseg;
            async16(ga, &As[(c0 * 16) * 32]);
            async16(ga + (size_t)16 * K, &As[(c0 * 16 + 16) * 32]);
            const unsigned short* gb = Bt + (size_t)(n0 + c0 * 16 + lrow) * K + k0 + lseg;
            async16(gb, &Bs[(c0 * 16) * 32]);
            async16(gb + (size_t)16 * K, &Bs[(c0 * 16 + 16) * 32]);
        }
        __syncthreads();
        short8 af[4], bf[4];
#pragma unroll
        for (int t = 0; t < 4; ++t) af[t] = *(const short8*)&As[(wi * 64 + t * 16) * 32 + fro];
#pragma unroll
        for (int t = 0; t < 4; ++t) bf[t] = *(const short8*)&Bs[(wj * 64 + t * 16) * 32 + fro];
#pragma unroll
        for (int it = 0; it < 4; ++it)
#pragma unroll
            for (int jt = 0; jt < 4; ++jt)
                acc[it][jt] = __builtin_amdgcn_mfma_f32_16x16x32_bf16(af[it], bf[jt], acc[it][jt], 0, 0, 0);
    }

    // epilogue: +bias, store transposed (bf16) as fpT[b][col][i], 8B packed stores
    const int b = i0 >> 11;
    const int il = i0 & 2047;
#pragma unroll
    for (int jt = 0; jt < 4; ++jt) {
        const int col = n0 + wj * 64 + jt * 16 + (lane & 15);
        const float cb = fc_b[col];
#pragma unroll
        for (int it = 0; it < 4; ++it) {
            const int rb = wi * 64 + it * 16 + ((lane >> 4) << 2);
            us4 o;
#pragma unroll
            for (int r = 0; r < 4; ++r) o[r] = f2bf(acc[it][jt][r] + cb);
            *(us4*)(fpT + ((size_t)b * HH + col) * NN + il + rb) = o;
        }
    }
}

// ---------------- K3: W[b,i,j] = adj * exp(lrelu(q_i+k_j)) (bf16), rZ = 1/rowsum ---
__global__ __launch_bounds__(256) void build_w_kernel(
    const float* __restrict__ adj, const float* __restrict__ q,
    const float* __restrict__ kk, unsigned short* __restrict__ Wd,
    float* __restrict__ rZ) {
    const int row = blockIdx.x;          // b*N + i
    const int b = row >> 11;
    const float qi = q[row];
    const float* arow = adj + (size_t)row * NN;
    const float* krow = kk + (b << 11);
    unsigned short* wrow = Wd + (size_t)row * NN;
    const int t = threadIdx.x;
    float z = 0.f;
#pragma unroll
    for (int rep = 0; rep < 2; ++rep) {
        const int j = rep * 1024 + t * 4;
        f32x4 a = *(const f32x4*)(arow + j);
        f32x4 kv = *(const f32x4*)(krow + j);
        us4 o;
#pragma unroll
        for (int c = 0; c < 4; ++c) {
            float s = qi + kv[c];
            s = (s >= 0.f) ? s : 0.01f * s;
            float wv = a[c] * __expf(s);
            z += wv;
            o[c] = f2bf(wv);
        }
        *(us4*)(wrow + j) = o;
    }
    for (int off = 32; off; off >>= 1) z += __shfl_down(z, off, 64);
    __shared__ float zr[4];
    if ((t & 63) == 0) zr[t >> 6] = z;
    __syncthreads();
    if (t == 0) rZ[row] = 1.0f / (zr[0] + zr[1] + zr[2] + zr[3]);
}

// ---------------- K4: out[b,i,h] = (sum_j W[b,i,j]*fpT[b,h,j]) * rZ_i + feats ------
__global__ __launch_bounds__(256) void gemm_out_kernel(
    const unsigned short* __restrict__ Wd, const unsigned short* __restrict__ fpT,
    const float* __restrict__ rZ, const float* __restrict__ feats,
    float* __restrict__ out) {
    __shared__ alignas(16) unsigned short As[128 * 32];
    __shared__ alignas(16) unsigned short Bs[128 * 32];
    const int tid = threadIdx.x;
    const int wave = tid >> 6, lane = tid & 63;
    const int wi = wave >> 1, wj = wave & 1;
    const int bid = blockIdx.x;
    const int b = bid & 7;               // batch == XCD for L2 locality of fpT[b]
    const int t6 = bid >> 3;             // 0..63
    const int i0 = (t6 >> 2) * 128;
    const int n0 = (t6 & 3) * 128;
    const int K = NN;
    const unsigned short* A = Wd + (size_t)b * NN * NN;
    const unsigned short* Bt = fpT + (size_t)b * HH * NN;

    f32x4 acc[4][4];
#pragma unroll
    for (int a = 0; a < 4; ++a)
#pragma unroll
        for (int c = 0; c < 4; ++c) acc[a][c] = (f32x4)(0.f);

    const int lrow = lane >> 2;
    const int lseg = (lane & 3) * 8;
    const int fro = (lane & 15) * 32 + (lane >> 4) * 8;

    for (int k0 = 0; k0 < K; k0 += 32) {
        __syncthreads();
        {
            const int c0 = wave * 2;
            const unsigned short* ga = A + (size_t)(i0 + c0 * 16 + lrow) * K + k0 + lseg;
            async16(ga, &As[(c0 * 16) * 32]);
            async16(ga + (size_t)16 * K, &As[(c0 * 16 + 16) * 32]);
            const unsigned short* gb = Bt + (size_t)(n0 + c0 * 16 + lrow) * K + k0 + lseg;
            async16(gb, &Bs[(c0 * 16) * 32]);
            async16(gb + (size_t)16 * K, &Bs[(c0 * 16 + 16) * 32]);
        }
        __syncthreads();
        short8 af[4], bf[4];
#pragma unroll
        for (int t = 0; t < 4; ++t) af[t] = *(const short8*)&As[(wi * 64 + t * 16) * 32 + fro];
#pragma unroll
        for (int t = 0; t < 4; ++t) bf[t] = *(const short8*)&Bs[(wj * 64 + t * 16) * 32 + fro];
#pragma unroll
        for (int it = 0; it < 4; ++it)
#pragma unroll
            for (int jt = 0; jt < 4; ++jt)
                acc[it][jt] = __builtin_amdgcn_mfma_f32_16x16x32_bf16(af[it], bf[jt], acc[it][jt], 0, 0, 0);
    }

    // epilogue: scale by 1/Z, add residual, store fp32
#pragma unroll
    for (int it = 0; it < 4; ++it) {
        const int rb = i0 + wi * 64 + it * 16 + ((lane >> 4) << 2);
        f32x4 rz4 = *(const f32x4*)(rZ + (b << 11) + rb);
#pragma unroll
        for (int jt = 0; jt < 4; ++jt) {
            const int col = n0 + wj * 64 + jt * 16 + (lane & 15);
#pragma unroll
            for (int r = 0; r < 4; ++r) {
                const size_t idx = ((size_t)(b << 11) + rb + r) * HH + col;
                out[idx] = acc[it][jt][r] * rz4[r] + feats[idx];
            }
        }
    }
}

extern "C" void kernel_launch(void* const* d_in, const int* in_sizes, int n_in,
                              void* d_out, int out_size, void* d_ws, size_t ws_size,
                              hipStream_t stream) {
    const float* feats = (const float*)d_in[0];
    const float* adj   = (const float*)d_in[1];
    const float* fc_w  = (const float*)d_in[2];
    const float* fc_b  = (const float*)d_in[3];
    const float* q_w   = (const float*)d_in[4];
    const float* q_b   = (const float*)d_in[5];
    const float* k_w   = (const float*)d_in[6];
    const float* k_b   = (const float*)d_in[7];
    float* out = (float*)d_out;

    char* w = (char*)d_ws;
    auto alloc = [&](size_t bytes) {
        char* p = w;
        w += (bytes + 255) & ~(size_t)255;
        return p;
    };
    unsigned short* feats_bf = (unsigned short*)alloc((size_t)BSZ * NN * HH * 2); // 16.8 MB
    unsigned short* fcw_bf   = (unsigned short*)alloc((size_t)HH * HH * 2);       // 0.5 MB
    float* wq  = (float*)alloc(HH * 4);
    float* wk  = (float*)alloc(HH * 4);
    float* bqk = (float*)alloc(256);
    float* qv  = (float*)alloc((size_t)BSZ * NN * 4);
    float* kv  = (float*)alloc((size_t)BSZ * NN * 4);
    float* rZ  = (float*)alloc((size_t)BSZ * NN * 4);
    unsigned short* fpT = (unsigned short*)alloc((size_t)BSZ * HH * NN * 2);      // 16.8 MB
    unsigned short* Wd  = (unsigned short*)alloc((size_t)BSZ * NN * NN * 2);      // 67 MB

    cvt_bf16_k<<<(BSZ * NN * HH / 4 + 255) / 256, 256, 0, stream>>>(feats, feats_bf, BSZ * NN * HH / 4);
    cvt_bf16_k<<<(HH * HH / 4 + 255) / 256, 256, 0, stream>>>(fc_w, fcw_bf, HH * HH / 4);
    eff_w_kernel<<<2, 256, 0, stream>>>(fc_w, fc_b, q_w, q_b, k_w, k_b, wq, wk, bqk);
    qk_kernel<<<BSZ * NN / 4, 256, 0, stream>>>(feats, wq, wk, bqk, qv, kv);
    gemm_fp_kernel<<<(BSZ * NN / 128) * (HH / 128), 256, 0, stream>>>(feats_bf, fcw_bf, fc_b, fpT);
    build_w_kernel<<<BSZ * NN, 256, 0, stream>>>(adj, qv, kv, Wd, rZ);
    gemm_out_kernel<<<BSZ * (NN / 128) * (HH / 128), 256, 0, stream>>>(Wd, fpT, rZ, feats, out);
}